// Round 1
// baseline (249.841 us; speedup 1.0000x reference)
//
#include <hip/hip_runtime.h>

// LengthRegulator: B=32, T=1024, D=384, T_OUT=4096
// out[b, p, :] = x[b, idx(p), :] for p < min(total_b, target_len_b), else 0,
// where idx(p) = the frame t whose cumulative-duration interval covers p.

#define BB 32
#define TT 1024
#define DD 384
#define TOUT 4096
#define D4 (DD / 4)   // 96 float4 per row

// Kernel 1: per-batch inclusive scan of durations in LDS, then interval
// scatter of frame index t into idx[b, ends[t-1] .. ends[t]).
__global__ __launch_bounds__(1024) void lr_scan_scatter(
    const int* __restrict__ dur,        // [B, T]
    const int* __restrict__ target_len, // [B]
    int* __restrict__ idx,              // [B, TOUT] (workspace)
    int* __restrict__ limit)            // [B]      (workspace)
{
    __shared__ int s[TT];
    const int b = blockIdx.x;
    const int t = threadIdx.x;

    int d = dur[b * TT + t];
    d = d > 0 ? d : 0;
    s[t] = d;
    __syncthreads();

    // Hillis-Steele inclusive scan over 1024 elements (10 steps).
    #pragma unroll
    for (int off = 1; off < TT; off <<= 1) {
        int v = (t >= off) ? s[t - off] : 0;
        __syncthreads();
        s[t] += v;
        __syncthreads();
    }

    const int e  = s[t];
    const int st = (t == 0) ? 0 : s[t - 1];

    if (t == TT - 1) {
        const int tot = e;
        const int tl  = target_len[b];
        limit[b] = tot < tl ? tot : tl;
    }

    // Scatter frame index over its output interval, clipped to TOUT.
    const int e2 = e < TOUT ? e : TOUT;
    const int s2 = st < TOUT ? st : TOUT;
    for (int p = s2; p < e2; ++p) {
        idx[b * TOUT + p] = t;
    }
}

// Kernel 2: one thread per output float4. Coalesced write; idx/limit loads
// are wave-broadcast L1 hits; x gather is row-coalesced.
__global__ __launch_bounds__(256) void lr_gather(
    const float4* __restrict__ x,     // [B, T, D4]
    const int* __restrict__ idx,      // [B, TOUT]
    const int* __restrict__ limit,    // [B]
    float4* __restrict__ out)         // [B, TOUT, D4]
{
    const int b = blockIdx.y;
    const int r = blockIdx.x * 256 + threadIdx.x; // 0 .. TOUT*D4
    const int p = r / D4;
    const int c = r - p * D4;

    const int lim = limit[b];
    float4 v = make_float4(0.f, 0.f, 0.f, 0.f);
    if (p < lim) {
        int t = idx[b * TOUT + p];
        t = t < 0 ? 0 : (t > TT - 1 ? TT - 1 : t);
        v = x[(b * TT + t) * D4 + c];
    }
    out[(b * TOUT + p) * D4 + c] = v;
}

extern "C" void kernel_launch(void* const* d_in, const int* in_sizes, int n_in,
                              void* d_out, int out_size, void* d_ws, size_t ws_size,
                              hipStream_t stream) {
    const float* x        = (const float*)d_in[0];
    const int* durations  = (const int*)d_in[1];
    const int* target_len = (const int*)d_in[2];
    float* out            = (float*)d_out;

    // Workspace layout: limit[32] at offset 0, idx[B*TOUT] at 256B offset.
    int* limit = (int*)d_ws;
    int* idx   = (int*)d_ws + 64;

    lr_scan_scatter<<<BB, TT, 0, stream>>>(durations, target_len, idx, limit);

    dim3 grid((TOUT * D4) / 256, BB);
    lr_gather<<<grid, 256, 0, stream>>>((const float4*)x, idx, limit, (float4*)out);
}